// Round 6
// baseline (102.735 us; speedup 1.0000x reference)
//
#include <hip/hip_runtime.h>
#include <math.h>

typedef float v2f __attribute__((ext_vector_type(2)));

static __device__ __forceinline__ v2f v2_min(v2f a, float b) {
    v2f r; r.x = fminf(a.x, b); r.y = fminf(a.y, b); return r;
}
static __device__ __forceinline__ v2f v2_max(v2f a, float b) {
    v2f r; r.x = fmaxf(a.x, b); r.y = fmaxf(a.y, b); return r;
}
static __device__ __forceinline__ v2f v2_max0(v2f a) {
    v2f r; r.x = fmaxf(a.x, 0.0f); r.y = fmaxf(a.y, 0.0f); return r;
}

// A=4 anchors per thread, block=128 -> each block covers 512 anchors.
// gt boxes delivered per-j via wave-uniform scalar loads (s_load), amortized
// over 4 anchors; no LDS, no __syncthreads, no separate prep launch.
__global__ __launch_bounds__(128) void rpn_match_kernel(
    const float* __restrict__ anchors,
    const float* __restrict__ deltas,
    const float* __restrict__ gt_boxes,
    float* __restrict__ out,
    int n, int m)
{
    const int tid = threadIdx.x;
    const int base = blockIdx.x * 512 + tid;

    int  idx[4];
    bool vld[4];
    float4 a[4], d[4];
    #pragma unroll
    for (int k = 0; k < 4; ++k) {
        int i = base + 128 * k;
        vld[k] = (i < n);
        idx[k] = vld[k] ? i : 0;
    }
    #pragma unroll
    for (int k = 0; k < 4; ++k) {
        a[k] = reinterpret_cast<const float4*>(anchors)[idx[k]];
        d[k] = reinterpret_cast<const float4*>(deltas)[idx[k]];
    }

    // ---- proposals (ulp-tolerant path; contraction allowed) ----
    const float SCALE_CLAMP = 3.3322045101752038f; // log(224/8)
    #pragma unroll
    for (int k = 0; k < 4; ++k) {
        float pw = (a[k].z - a[k].x) * 0.5f, ph = (a[k].w - a[k].y) * 0.5f;
        float px = (a[k].x + a[k].z) * 0.5f, py = (a[k].y + a[k].w) * 0.5f;
        float bx = px + pw * d[k].x, by = py + ph * d[k].y;
        float bw = pw * expf(fminf(d[k].z, SCALE_CLAMP));
        float bh = ph * expf(fminf(d[k].w, SCALE_CLAMP));
        if (vld[k]) reinterpret_cast<float4*>(out)[idx[k]] =
            make_float4(bx - bw, by - bh, bx + bw, by + bh);
    }

    // ---- divide-free IoU argmax, bit-faithful: no fp contraction here ----
    // iou_j > iou_b  <=>  inter_j*S_b > inter_b*S_j   (S = area1+area2 > 0)
    {
        #pragma clang fp contract(off)
        v2f ax[2], ay[2], az[2], aw[2], ar[2], bI[2], bS[2];
        int bidx[4];
        #pragma unroll
        for (int p = 0; p < 2; ++p) {
            ax[p].x = a[2*p].x;   ax[p].y = a[2*p+1].x;
            ay[p].x = a[2*p].y;   ay[p].y = a[2*p+1].y;
            az[p].x = a[2*p].z;   az[p].y = a[2*p+1].z;
            aw[p].x = a[2*p].w;   aw[p].y = a[2*p+1].w;
            ar[p].x = (a[2*p].z   - a[2*p].x)   * (a[2*p].w   - a[2*p].y);
            ar[p].y = (a[2*p+1].z - a[2*p+1].x) * (a[2*p+1].w - a[2*p+1].y);
            // init so j==0 always wins the first compare: lhs>=0 > -S = rhs
            bI[p].x = -1.0f; bI[p].y = -1.0f;
            bS[p].x =  1.0f; bS[p].y =  1.0f;
        }
        bidx[0] = bidx[1] = bidx[2] = bidx[3] = 0;

        #pragma unroll 8
        for (int j = 0; j < m; ++j) {
            // wave-uniform gt row -> scalar loads (merged s_load_dwordx4 + dword)
            float g0 = gt_boxes[j * 5 + 0];
            float g1 = gt_boxes[j * 5 + 1];
            float g2 = gt_boxes[j * 5 + 2];
            float g3 = gt_boxes[j * 5 + 3];
            float g4 = gt_boxes[j * 5 + 4];
            bool valid = (g4 != -1.0f);
            // invalid -> (0,0,0,0): inter==0 vs any anchor (anchor x1>=8>0),
            // area 0; can never win argmax; trivial win => q<=IOU_LOW path.
            g0 = valid ? g0 : 0.0f;
            g1 = valid ? g1 : 0.0f;
            g2 = valid ? g2 : 0.0f;
            g3 = valid ? g3 : 0.0f;
            float ga = (g2 - g0) * (g3 - g1);  // separately rounded, as ref

            #pragma unroll
            for (int p = 0; p < 2; ++p) {
                v2f xl = v2_min(az[p], g2) - v2_max(ax[p], g0);
                v2f yl = v2_min(aw[p], g3) - v2_max(ay[p], g1);
                v2f inter = v2_max0(xl) * v2_max0(yl);
                v2f S = ar[p] + ga;
                v2f lhs = inter * bS[p];
                v2f rhs = bI[p] * S;
                bool w0 = lhs.x > rhs.x;   // strict > = first-occurrence argmax
                bool w1 = lhs.y > rhs.y;
                bI[p].x   = w0 ? inter.x : bI[p].x;
                bS[p].x   = w0 ? S.x     : bS[p].x;
                bidx[2*p] = w0 ? j       : bidx[2*p];
                bI[p].y     = w1 ? inter.y : bI[p].y;
                bS[p].y     = w1 ? S.y     : bS[p].y;
                bidx[2*p+1] = w1 ? j       : bidx[2*p+1];
            }
        }

        // ---- epilogue: one exact divide per anchor, classify, gather, store ----
        const float IOU_LOW = 0.3f, IOU_HIGH = 0.6f, NEUTRAL = -100000000.0f;
        float* mout = out + (size_t)n * 4;

        #pragma unroll
        for (int k = 0; k < 4; ++k) {
            float I = (k & 1) ? bI[k >> 1].y : bI[k >> 1].x;
            float S = (k & 1) ? bS[k >> 1].y : bS[k >> 1].x;
            float uni = S - I;     // fl(fl(a1+a2) - inter): same assoc as ref
            float q = I / uni;     // bit-identical to ref match_quality
            float o0, o1, o2, o3, o4;
            if (q <= IOU_LOW) {
                o0 = o1 = o2 = o3 = o4 = -1.0f;
            } else if (q < IOU_HIGH) {
                o0 = o1 = o2 = o3 = o4 = NEUTRAL;
            } else {
                const float* row = gt_boxes + (size_t)bidx[k] * 5;  // raw gt row, as ref
                o0 = row[0]; o1 = row[1]; o2 = row[2]; o3 = row[3]; o4 = row[4];
            }
            if (vld[k]) {
                float* mo = mout + (size_t)idx[k] * 5;
                mo[0] = o0; mo[1] = o1; mo[2] = o2; mo[3] = o3; mo[4] = o4;
            }
        }
    }
}

extern "C" void kernel_launch(void* const* d_in, const int* in_sizes, int n_in,
                              void* d_out, int out_size, void* d_ws, size_t ws_size,
                              hipStream_t stream) {
    const float* anchors  = (const float*)d_in[0];
    const float* deltas   = (const float*)d_in[1];
    const float* gt_boxes = (const float*)d_in[2];
    float* out = (float*)d_out;

    int n = in_sizes[0] / 4;   // 400000
    int m = in_sizes[2] / 5;   // 128

    int nblocks = (n + 511) / 512;   // 4 anchors/thread, 128-thread blocks
    hipLaunchKernelGGL(rpn_match_kernel, dim3(nblocks), dim3(128), 0, stream,
                       anchors, deltas, gt_boxes, out, n, m);
}

// Round 7
// 100.892 us; speedup vs baseline: 1.0183x; 1.0183x over previous
//
#include <hip/hip_runtime.h>
#include <math.h>

// A=1 anchor per thread, block=256 -> 400K threads, ~24 waves/CU.
// Evidence (R1/R2/R6): this kernel is latency-bound; VALUBusy tracks
// occupancy. So maximize TLP and keep the inner loop minimal.
// gt rows delivered per-j via wave-uniform loads (scalar-load path).
__global__ __launch_bounds__(256) void rpn_match_kernel(
    const float* __restrict__ anchors,
    const float* __restrict__ deltas,
    const float* __restrict__ gt_boxes,
    float* __restrict__ out,
    int n, int m)
{
    const int i = blockIdx.x * 256 + threadIdx.x;
    if (i >= n) return;

    const float4 a = reinterpret_cast<const float4*>(anchors)[i];
    const float4 d = reinterpret_cast<const float4*>(deltas)[i];

    // ---- proposals (ulp-tolerant path; contraction allowed) ----
    const float SCALE_CLAMP = 3.3322045101752038f; // log(224/8)
    {
        float pw = (a.z - a.x) * 0.5f, ph = (a.w - a.y) * 0.5f;
        float px = (a.x + a.z) * 0.5f, py = (a.y + a.w) * 0.5f;
        float bx = px + pw * d.x, by = py + ph * d.y;
        float bw = pw * expf(fminf(d.z, SCALE_CLAMP));
        float bh = ph * expf(fminf(d.w, SCALE_CLAMP));
        reinterpret_cast<float4*>(out)[i] =
            make_float4(bx - bw, by - bh, bx + bw, by + bh);
    }

    // ---- divide-free IoU argmax (bit-faithful: no contraction) ----
    // iou_j > iou_b  <=>  inter_j*S_b > inter_b*S_j   (S = area1+area2 > 0)
    {
        #pragma clang fp contract(off)
        const float ar = (a.z - a.x) * (a.w - a.y);

        // init so j==0 always wins the first compare: lhs = I0*1 >= 0 > -S0
        float bI = -1.0f, bS = 1.0f;
        int bidx = 0;

        #pragma unroll 8
        for (int j = 0; j < m; ++j) {
            // wave-uniform gt row (scalar-load path, hoisted by unroll)
            float g0 = gt_boxes[j * 5 + 0];
            float g1 = gt_boxes[j * 5 + 1];
            float g2 = gt_boxes[j * 5 + 2];
            float g3 = gt_boxes[j * 5 + 3];
            float g4 = gt_boxes[j * 5 + 4];
            float ga = (g2 - g0) * (g3 - g1);   // separately rounded, as ref
            // invalid gt -> S = inf: can never displace a positive best
            // (rhs = bI*inf = inf, or NaN when bI==0 -> strict '>' false);
            // a trivial early win gives q = inter/inf = 0 <= IOU_LOW ->
            // index-independent -1 fill, same as ref's m = -1 column.
            ga = (g4 != -1.0f) ? ga : __builtin_inff();

            float x1 = fmaxf(a.x, g0);
            float y1 = fmaxf(a.y, g1);
            float x2 = fminf(a.z, g2);
            float y2 = fminf(a.w, g3);
            float xl = x2 - x1;
            float yl = y2 - y1;
            float inter = fmaxf(xl, 0.0f) * fmaxf(yl, 0.0f);
            float S = ar + ga;
            bool w = (inter * bS) > (bI * S);  // strict > = first-occurrence
            bI   = w ? inter : bI;
            bS   = w ? S     : bS;
            bidx = w ? j     : bidx;
        }

        // ---- epilogue: one exact divide, classify, gather, store ----
        const float IOU_LOW = 0.3f, IOU_HIGH = 0.6f, NEUTRAL = -100000000.0f;
        float uni = bS - bI;   // fl(fl(a1+a2) - inter): same assoc as ref
        float q = bI / uni;    // bit-identical to ref match_quality
        float o0, o1, o2, o3, o4;
        if (q <= IOU_LOW) {
            o0 = o1 = o2 = o3 = o4 = -1.0f;
        } else if (q < IOU_HIGH) {
            o0 = o1 = o2 = o3 = o4 = NEUTRAL;
        } else {
            const float* row = gt_boxes + (size_t)bidx * 5;  // raw gt row, as ref
            o0 = row[0]; o1 = row[1]; o2 = row[2]; o3 = row[3]; o4 = row[4];
        }
        float* mo = out + (size_t)n * 4 + (size_t)i * 5;
        mo[0] = o0; mo[1] = o1; mo[2] = o2; mo[3] = o3; mo[4] = o4;
    }
}

extern "C" void kernel_launch(void* const* d_in, const int* in_sizes, int n_in,
                              void* d_out, int out_size, void* d_ws, size_t ws_size,
                              hipStream_t stream) {
    const float* anchors  = (const float*)d_in[0];
    const float* deltas   = (const float*)d_in[1];
    const float* gt_boxes = (const float*)d_in[2];
    float* out = (float*)d_out;

    int n = in_sizes[0] / 4;   // 400000
    int m = in_sizes[2] / 5;   // 128

    int nblocks = (n + 255) / 256;   // 1 anchor/thread, max TLP
    hipLaunchKernelGGL(rpn_match_kernel, dim3(nblocks), dim3(256), 0, stream,
                       anchors, deltas, gt_boxes, out, n, m);
}